// Round 18
// baseline (1330.029 us; speedup 1.0000x reference)
//
#include <hip/hip_runtime.h>
#include <stdint.h>

// GreatNet: agent/context edge MLP.
//   sort:           hw[pos] = packed (h,w) sorted by h (hist + 3-pass scan + scatter)
//   k_wprep:        pre-swizzle w1d/wc2 -> bf16 global (L2-resident weight reads)
//   k_ctx:          CtxP[j]  = ctx[j] @ W1c^T                       (bf16, ws)
//   k_agent_pre_mfma: QW[i]  = relu(gn(agts[i]@q_w^T)) @ W1q^T      (bf16, ws)
//                   A0[i]    = agts[i] @ agt_w^T                    (f32, d_out)
//   k_edge_mfma:    BARRIER-FREE, SORTED, 64KB LDS -> 2 blocks/CU (16 waves):
//                   wd2 in LDS (mm1, latency-critical); w1d/wc2 B-frags read
//                   from L2 via identical swizzled layout. Run-segmented atomics.
//   k_post_mfma:    a=relu(gn(A0)); t=gn(a@lin_w^T); out=relu(t+agts)

#define N_AGT 100000
#define N_CTX 10000
#define NE    1000000
#define D     128

typedef __attribute__((ext_vector_type(8))) __bf16 bf16x8;
typedef __attribute__((ext_vector_type(4))) float f32x4;
typedef __attribute__((ext_vector_type(4))) unsigned int uint32x4;
typedef __attribute__((ext_vector_type(8))) unsigned short ushort8;

__device__ __forceinline__ float bf_lo(uint32_t u){ return __uint_as_float(u << 16); }
__device__ __forceinline__ float bf_hi(uint32_t u){ return __uint_as_float(u & 0xFFFF0000u); }
__device__ __forceinline__ uint16_t f2bf(float f){
  uint32_t u = __float_as_uint(f);
  u += 0x7FFFu + ((u >> 16) & 1u);   // round-to-nearest-even
  return (uint16_t)(u >> 16);
}
__device__ __forceinline__ uint16_t f2bf_fast(float f){
  const __bf16 b = (__bf16)f;
  return __builtin_bit_cast(uint16_t, b);
}
__device__ __forceinline__ float bf2f(uint16_t v){ return __uint_as_float(((uint32_t)v) << 16); }

__device__ __forceinline__ f32x4 mfma16(bf16x8 a, bf16x8 b, f32x4 c){
  return __builtin_amdgcn_mfma_f32_16x16x32_bf16(a, b, c, 0, 0, 0);
}

// within-wave LDS ordering (write->read same buffer); NO barrier, NO vmcnt.
__device__ __forceinline__ void wave_lgkm0(){
  asm volatile("s_waitcnt lgkmcnt(0)" ::: "memory");
  __builtin_amdgcn_sched_barrier(0);   // rule #18 fence
}

// ---- shared MFMA tile machinery (swizzle: phys = row*256 + (byte ^ ((row&7)<<4))) ----

__device__ __forceinline__ void stage_wsz(char* dst, const float* __restrict__ W,
                                          int rs, int co, int tid, int nthr){
  for (int idx = tid; idx < 128*16; idx += nthr){
    const int row = idx >> 4, ch = idx & 15;
    const float4 f0 = *(const float4*)(W + (size_t)row*rs + co + ch*8);
    const float4 f1 = *(const float4*)(W + (size_t)row*rs + co + ch*8 + 4);
    ushort8 u;
    u[0]=f2bf(f0.x); u[1]=f2bf(f0.y); u[2]=f2bf(f0.z); u[3]=f2bf(f0.w);
    u[4]=f2bf(f1.x); u[5]=f2bf(f1.y); u[6]=f2bf(f1.z); u[7]=f2bf(f1.w);
    *(uint32x4*)(dst + row*256 + ((ch*16) ^ ((row&7)<<4))) = __builtin_bit_cast(uint32x4, u);
  }
}

__device__ __forceinline__ bf16x8 ldfrag(const char* base, int row, int cb){
  return __builtin_bit_cast(bf16x8,
      *(const uint32x4*)(base + row*256 + (cb ^ ((row&7)<<4))));
}

// ======================= weight prep: swizzled bf16 copies in global =======================
__global__ __launch_bounds__(256) void k_wprep(const float* __restrict__ ctx_w1,
                                               const float* __restrict__ ctx_w2,
                                               char* __restrict__ w1dg,
                                               char* __restrict__ wc2g){
  const int t = blockIdx.x*256 + threadIdx.x;   // 0 .. 2*2048-1
  if (t >= 2*2048) return;
  const int m = t >> 11, idx = t & 2047;
  const float* W = m ? ctx_w2 : ctx_w1;
  const int rs = m ? 128 : 384;
  char* dst = m ? wc2g : w1dg;
  const int row = idx >> 4, ch = idx & 15;
  const float4 f0 = *(const float4*)(W + (size_t)row*rs + ch*8);
  const float4 f1 = *(const float4*)(W + (size_t)row*rs + ch*8 + 4);
  ushort8 u;
  u[0]=f2bf(f0.x); u[1]=f2bf(f0.y); u[2]=f2bf(f0.z); u[3]=f2bf(f0.w);
  u[4]=f2bf(f1.x); u[5]=f2bf(f1.y); u[6]=f2bf(f1.z); u[7]=f2bf(f1.w);
  *(uint32x4*)(dst + row*256 + ((ch*16) ^ ((row&7)<<4))) = __builtin_bit_cast(uint32x4, u);
}

// ======================= sort-by-hi (counting sort, parallel scan) =======================
#define SCAN_B  256
#define SCAN_CH ((N_AGT + SCAN_B - 1) / SCAN_B)   // 391

__global__ __launch_bounds__(256) void k_hist(const int* __restrict__ hi,
                                              int* __restrict__ cnt){
  for (int i = blockIdx.x*256 + threadIdx.x; i < NE; i += gridDim.x*256)
    atomicAdd(&cnt[hi[i]], 1);
}

__global__ __launch_bounds__(256) void k_scan1(const int* __restrict__ cnt,
                                               int* __restrict__ bsum){
  __shared__ int red[4];
  const int b = blockIdx.x, t = threadIdx.x;
  const int lo = b*SCAN_CH, hiX = min(lo + SCAN_CH, N_AGT);
  int s = 0;
  for (int i = lo + t; i < hiX; i += 256) s += cnt[i];
  #pragma unroll
  for (int m = 1; m < 64; m <<= 1) s += __shfl_xor(s, m);
  if ((t & 63) == 0) red[t >> 6] = s;
  __syncthreads();
  if (t == 0) bsum[b] = red[0] + red[1] + red[2] + red[3];
}

__global__ __launch_bounds__(SCAN_B) void k_scan2(int* __restrict__ bsum){
  __shared__ int part[SCAN_B];
  const int t = threadIdx.x;
  const int v = bsum[t];
  part[t] = v;
  __syncthreads();
  for (int ofs = 1; ofs < SCAN_B; ofs <<= 1){
    const int add = (t >= ofs) ? part[t - ofs] : 0;
    __syncthreads();
    part[t] += add;
    __syncthreads();
  }
  bsum[t] = part[t] - v;   // exclusive
}

__global__ __launch_bounds__(256) void k_scan3(int* __restrict__ cnt,
                                               const int* __restrict__ bsum){
  __shared__ int tpart[256];
  const int b = blockIdx.x, t = threadIdx.x;
  const int lo = b*SCAN_CH, hiX = min(lo + SCAN_CH, N_AGT);
  const int per = (SCAN_CH + 255) / 256;           // 2
  const int s0 = lo + t*per, s1 = min(s0 + per, hiX);
  int s = 0;
  for (int i = s0; i < s1; i++) s += cnt[i];
  tpart[t] = s;
  __syncthreads();
  for (int ofs = 1; ofs < 256; ofs <<= 1){
    const int add = (t >= ofs) ? tpart[t - ofs] : 0;
    __syncthreads();
    tpart[t] += add;
    __syncthreads();
  }
  int run = bsum[b] + tpart[t] - s;
  for (int i = s0; i < s1; i++){
    const int c = cnt[i];
    cnt[i] = run;
    run += c;
  }
}

__global__ __launch_bounds__(256) void k_scatter(const int* __restrict__ hi,
                                                 const int* __restrict__ wi,
                                                 int* __restrict__ cur,
                                                 uint64_t* __restrict__ hw){
  for (int i = blockIdx.x*256 + threadIdx.x; i < NE; i += gridDim.x*256){
    const int h = hi[i];
    const int pos = atomicAdd(&cur[h], 1);
    hw[pos] = ((uint64_t)(uint32_t)wi[i] << 32) | (uint32_t)h;
  }
}

// ======================= k_edge_mfma (barrier-free, sorted, 2 blocks/CU) =======================
// 512 thr = 8 waves; wave owns 16 sorted edges/iter, private 4KB tile T.
// LDS: [0) wd2 32768 | [32768) T: 8 waves x 4096  -> 65536 B => 2 blocks/CU.
// w1d/wc2 B-fragments read from L2 (swizzled bf16 copies in ws).
#define NWIT (NE/16)     // 62500 wave-iterations total (exact)

__device__ __forceinline__ void mm16(const char* T, const char* W,
                                     int llo, int lhi, f32x4 acc[8]){
  bf16x8 a[4];
  #pragma unroll
  for (int kt = 0; kt < 4; kt++) a[kt] = ldfrag(T, llo, kt*64 + lhi*16);
  #pragma unroll
  for (int nt = 0; nt < 8; nt++){
    acc[nt] = (f32x4)0.f;
    #pragma unroll
    for (int kt = 0; kt < 4; kt++){
      const bf16x8 b = ldfrag(W, nt*16 + llo, kt*64 + lhi*16);
      acc[nt] = mfma16(a[kt], b, acc[nt]);
    }
  }
}

__device__ __forceinline__ void gn_reg(f32x4 acc[8], const float gw[8],
                                       const float gb[8]){
  float s[4] = {0,0,0,0}, ss[4] = {0,0,0,0};
  #pragma unroll
  for (int nt = 0; nt < 8; nt++)
    #pragma unroll
    for (int r = 0; r < 4; r++){
      const float v = acc[nt][r];
      s[r] += v; ss[r] += v*v;
    }
  #pragma unroll
  for (int m = 1; m < 16; m <<= 1)
    #pragma unroll
    for (int r = 0; r < 4; r++){
      s[r] += __shfl_xor(s[r], m);
      ss[r] += __shfl_xor(ss[r], m);
    }
  float mean[4], rstd[4];
  #pragma unroll
  for (int r = 0; r < 4; r++){
    mean[r] = s[r]*(1.f/128.f);
    const float var = ss[r]*(1.f/128.f) - mean[r]*mean[r];
    rstd[r] = rsqrtf(var + 1e-5f);
  }
  #pragma unroll
  for (int nt = 0; nt < 8; nt++)
    #pragma unroll
    for (int r = 0; r < 4; r++)
      acc[nt][r] = fmaxf((acc[nt][r]-mean[r])*rstd[r]*gw[nt] + gb[nt], 0.f);
}

__device__ __forceinline__ void scat16(char* T, const f32x4 acc[8],
                                       int llo, int lhi){
  #pragma unroll
  for (int nt = 0; nt < 8; nt++)
    #pragma unroll
    for (int r = 0; r < 4; r++){
      const int row = lhi*4 + r;
      *(uint16_t*)(T + row*256 + ((2*(nt*16 + llo)) ^ ((row&7)<<4))) =
          f2bf_fast(acc[nt][r]);
    }
}

__global__ __launch_bounds__(512, 2) void k_edge_mfma(
    const float* __restrict__ agt_ctrs, const float* __restrict__ ctx_ctrs,
    const uint32_t* __restrict__ hw32,
    const float* __restrict__ dist_w1, const float* __restrict__ dist_b1,
    const float* __restrict__ dist_gw, const float* __restrict__ dist_gb,
    const float* __restrict__ ctx_gw, const float* __restrict__ ctx_gb,
    const float* __restrict__ dist_w2,
    const char* __restrict__ w1dg, const char* __restrict__ wc2g,
    const uint16_t* __restrict__ QW, const uint16_t* __restrict__ CtxP,
    float* __restrict__ A0){
  extern __shared__ __align__(16) char smem[];
  const int tid  = threadIdx.x;
  const int wave = tid >> 6, lane = tid & 63;
  const int lhi  = lane >> 4, llo = lane & 15;

  stage_wsz(smem, dist_w2, 128, 0, tid, 512);    // wd2 in LDS (mm1)

  char* T = smem + 32768 + wave*4096;   // private 16x256B swizzled tile

  const int c0 = llo*8;                 // d1-build cols
  float w1x[8], w1y[8], b1v[8];
  #pragma unroll
  for (int j = 0; j < 8; j++){
    w1x[j] = dist_w1[(c0+j)*2 + 0];
    w1y[j] = dist_w1[(c0+j)*2 + 1];
    b1v[j] = dist_b1[c0+j];
  }
  float dgwr[8], dgbr[8], cgwr[8], cgbr[8];   // GN cols nt*16+llo
  #pragma unroll
  for (int nt = 0; nt < 8; nt++){
    dgwr[nt] = dist_gw[nt*16 + llo]; dgbr[nt] = dist_gb[nt*16 + llo];
    cgwr[nt] = ctx_gw[nt*16 + llo];  cgbr[nt] = ctx_gb[nt*16 + llo];
  }
  __syncthreads();   // weights staged — the ONLY block barrier

  const int wid = blockIdx.x*8 + wave;
  const int nw  = gridDim.x*8;

  for (int i = wid; i < NWIT; i += nw){
    const int base = i*16;
    // ---- A: packed indices + qs-issue + d1 build into T ----
    const uint32x4 q0 = *(const uint32x4*)&hw32[2*(base + lhi*4)];      // edges +0,+1
    const uint32x4 q1 = *(const uint32x4*)&hw32[2*(base + lhi*4) + 4];  // edges +2,+3
    const int hh[4] = {(int)q0[0], (int)q0[2], (int)q1[0], (int)q1[2]};
    const int ww[4] = {(int)q0[1], (int)q0[3], (int)q1[1], (int)q1[3]};
    const uint2 p2 = *(const uint2*)&hw32[2*(base + llo)];
    const int h2 = (int)p2.x, w2 = (int)p2.y;
    uint32x4 qql[4], qcl[4];               // qs gathers: land by phase E
    #pragma unroll
    for (int k = 0; k < 4; k++){
      qql[k] = *(const uint32x4*)&QW  [(size_t)h2*D + lhi*32 + k*8];
      qcl[k] = *(const uint32x4*)&CtxP[(size_t)w2*D + lhi*32 + k*8];
    }
    #pragma unroll
    for (int j = 0; j < 4; j++){
      const float2 ac = *(const float2*)&agt_ctrs[(size_t)hh[j]*2];
      const float2 cc = *(const float2*)&ctx_ctrs[(size_t)ww[j]*2];
      const float dx = ac.x - cc.x, dy = ac.y - cc.y;
      ushort8 u;
      #pragma unroll
      for (int c = 0; c < 8; c++)
        u[c] = f2bf_fast(fmaxf(fmaf(dx, w1x[c], fmaf(dy, w1y[c], b1v[c])), 0.f));
      const int row = lhi*4 + j;
      *(uint32x4*)(T + row*256 + ((llo*16) ^ ((row&7)<<4))) =
          __builtin_bit_cast(uint32x4, u);
    }
    wave_lgkm0();                           // d1 visible to this wave
    // ---- B: mm1 z = d1 @ wd2^T (LDS weights) ----
    f32x4 acc[8];
    mm16(T, smem, llo, lhi, acc);
    // ---- C: gn1 on regs + scatter d -> T ----
    gn_reg(acc, dgwr, dgbr);
    wave_lgkm0();                           // T reads (mm1) retired
    scat16(T, acc, llo, lhi);
    wave_lgkm0();
    // ---- D: mm2 raw = d @ w1d^T (L2 weights) ----
    mm16(T, w1dg, llo, lhi, acc);
    // ---- E: qs -> T (edge-layout), read back at C positions, gn2 ----
    ushort8 qs[4];
    #pragma unroll
    for (int k = 0; k < 4; k++){
      const ushort8 a = __builtin_bit_cast(ushort8, qql[k]);
      const ushort8 b = __builtin_bit_cast(ushort8, qcl[k]);
      ushort8 v;
      #pragma unroll
      for (int j = 0; j < 8; j++) v[j] = f2bf_fast(bf2f(a[j]) + bf2f(b[j]));
      qs[k] = v;
    }
    wave_lgkm0();                           // T reads (mm2) retired
    #pragma unroll
    for (int k = 0; k < 4; k++)             // write qs: row llo, elems lhi*32+k*8
      *(uint32x4*)(T + llo*256 + (((lhi*64) + k*16) ^ ((llo&7)<<4))) =
          __builtin_bit_cast(uint32x4, qs[k]);
    wave_lgkm0();
    #pragma unroll
    for (int nt = 0; nt < 8; nt++)
      #pragma unroll
      for (int r = 0; r < 4; r++){
        const int row = lhi*4 + r;
        const uint16_t q = *(const uint16_t*)(T + row*256 +
            ((2*(nt*16 + llo)) ^ ((row&7)<<4)));
        acc[nt][r] += bf2f(q);
      }
    gn_reg(acc, cgwr, cgbr);
    wave_lgkm0();                           // qs reads retired
    scat16(T, acc, llo, lhi);               // T = c1
    wave_lgkm0();
    // ---- F: mm3 c = c1 @ wc2^T (L2 weights) ----
    mm16(T, wc2g, llo, lhi, acc);
    // ---- G: scatter c -> T, run-segmented column aggregation, atomics ----
    wave_lgkm0();                           // T reads (mm3) retired
    scat16(T, acc, llo, lhi);               // T = c (bf16)
    wave_lgkm0();
    {
      const int cA = lane, cB = lane + 64;  // lane owns 2 output columns
      float runA = 0.f, runB = 0.f;
      int hprev = __shfl(h2, 0);            // hs[base] (wave-uniform)
      #pragma unroll
      for (int k = 0; k < 16; k++){
        const int hk = __shfl(h2, k);       // uniform -> scalar branch
        if (hk != hprev){
          atomicAdd(&A0[(size_t)hprev*D + cA], runA);
          atomicAdd(&A0[(size_t)hprev*D + cB], runB);
          runA = 0.f; runB = 0.f; hprev = hk;
        }
        runA += bf2f(*(const uint16_t*)(T + k*256 + ((2*cA) ^ ((k&7)<<4))));
        runB += bf2f(*(const uint16_t*)(T + k*256 + ((2*cB) ^ ((k&7)<<4))));
      }
      atomicAdd(&A0[(size_t)hprev*D + cA], runA);
      atomicAdd(&A0[(size_t)hprev*D + cB], runB);
    }
    // no barrier: next iter's T writes are in-order after this iter's T reads
  }
}

// ======================= k_agent_pre_mfma (unchanged) =======================
__device__ __forceinline__ void mm_stage(const char* xb, const char* wm, int wv,
                                         int llo, int lhi, f32x4 acc[3][2]){
  #pragma unroll
  for (int kt = 0; kt < 4; kt++){
    const int cb = kt*64 + lhi*16;
    const bf16x8 b0 = ldfrag(wm, wv*32 + llo,      cb);
    const bf16x8 b1 = ldfrag(wm, wv*32 + 16 + llo, cb);
    #pragma unroll
    for (int mt = 0; mt < 3; mt++){
      const bf16x8 a = ldfrag(xb, mt*16 + llo, cb);
      acc[mt][0] = mfma16(a, b0, acc[mt][0]);
      acc[mt][1] = mfma16(a, b1, acc[mt][1]);
    }
  }
}

__device__ __forceinline__ void scat_acc(char* xb, const f32x4 acc[3][2],
                                         int wv, int llo, int lhi){
  #pragma unroll
  for (int mt = 0; mt < 3; mt++)
    #pragma unroll
    for (int ntl = 0; ntl < 2; ntl++)
      #pragma unroll
      for (int r = 0; r < 4; r++){
        const int m = mt*16 + lhi*4 + r;
        const int n = wv*32 + ntl*16 + llo;
        *(uint16_t*)(xb + m*256 + ((n*2) ^ ((m&7)<<4))) = f2bf(acc[mt][ntl][r]);
      }
}

__device__ __forceinline__ void gn_rowpass(char* xb, const int rr[3], int llo,
                                           const float gw[8], const float gb[8]){
  #pragma unroll
  for (int i = 0; i < 3; i++){
    const int row = rr[i];
    char* p = xb + row*256 + ((llo*16) ^ ((row&7)<<4));
    ushort8 u = __builtin_bit_cast(ushort8, *(const uint32x4*)p);
    float f[8]; float s = 0.f, ss = 0.f;
    #pragma unroll
    for (int j = 0; j < 8; j++){ f[j] = bf2f(u[j]); s += f[j]; ss += f[j]*f[j]; }
    #pragma unroll
    for (int m = 1; m < 16; m <<= 1){ s += __shfl_xor(s, m); ss += __shfl_xor(ss, m); }
    const float mean = s*(1.f/128.f);
    const float var  = ss*(1.f/128.f) - mean*mean;
    const float rstd = rsqrtf(var + 1e-5f);
    #pragma unroll
    for (int j = 0; j < 8; j++){
      const float g = fmaxf((f[j]-mean)*rstd*gw[j] + gb[j], 0.f);
      u[j] = f2bf(g);
    }
    *(uint32x4*)p = __builtin_bit_cast(uint32x4, u);
  }
}

#define NITER_A ((N_AGT + 95) / 96)

__global__ __launch_bounds__(512, 2) void k_agent_pre_mfma(
    const float* __restrict__ agts, const float* __restrict__ q_w,
    const float* __restrict__ ctx_w1, const float* __restrict__ agt_w,
    const float* __restrict__ q_gw, const float* __restrict__ q_gb,
    uint16_t* __restrict__ QW, float* __restrict__ A0){
  extern __shared__ __align__(16) char smem[];
  const int tid  = threadIdx.x;
  const int wave = tid >> 6, lane = tid & 63;
  const int grp  = wave >> 2, wv = wave & 3;
  const int lhi  = lane >> 4, llo = lane & 15;

  stage_wsz(smem,         q_w,    128, 0,   tid, 512);
  stage_wsz(smem + 32768, agt_w,  128, 0,   tid, 512);
  stage_wsz(smem + 65536, ctx_w1, 384, 128, tid, 512);

  char* xb = smem + 98304 + grp*12288;
  const int c0 = llo*8;
  float qgw[8], qgb[8];
  #pragma unroll
  for (int j = 0; j < 8; j++){ qgw[j] = q_gw[c0+j]; qgb[j] = q_gb[c0+j]; }
  __syncthreads();

  const int tg = tid & 255;
  int rr[3];
  #pragma unroll
  for (int i = 0; i < 3; i++) rr[i] = wv*12 + i*4 + lhi;

  for (int it = blockIdx.x; it < NITER_A; it += gridDim.x){
    const int rbase = it*96 + grp*48;
    for (int idx = tg; idx < 48*32; idx += 256){
      const int row = idx >> 5, c4 = idx & 31;
      int gr = rbase + row; if (gr >= N_AGT) gr = N_AGT - 1;
      const float4 f = *(const float4*)(agts + (size_t)gr*D + c4*4);
      const uint32_t lo = ((uint32_t)f2bf(f.y) << 16) | (uint32_t)f2bf(f.x);
      const uint32_t hi2 = ((uint32_t)f2bf(f.w) << 16) | (uint32_t)f2bf(f.z);
      *(uint2*)(xb + row*256 + ((c4*8) ^ ((row&7)<<4))) = make_uint2(lo, hi2);
    }
    __syncthreads();
    f32x4 acc[3][2];
    #pragma unroll
    for (int mt = 0; mt < 3; mt++){ acc[mt][0] = (f32x4)0.f; acc[mt][1] = (f32x4)0.f; }
    mm_stage(xb, smem + 32768, wv, llo, lhi, acc);
    #pragma unroll
    for (int mt = 0; mt < 3; mt++)
      #pragma unroll
      for (int ntl = 0; ntl < 2; ntl++)
        #pragma unroll
        for (int r = 0; r < 4; r++){
          const int m = mt*16 + lhi*4 + r;
          if (rbase + m < N_AGT){
            const int n = wv*32 + ntl*16 + llo;
            A0[(size_t)(rbase + m)*D + n] = acc[mt][ntl][r];
          }
        }
    #pragma unroll
    for (int mt = 0; mt < 3; mt++){ acc[mt][0] = (f32x4)0.f; acc[mt][1] = (f32x4)0.f; }
    mm_stage(xb, smem, wv, llo, lhi, acc);
    __syncthreads();
    scat_acc(xb, acc, wv, llo, lhi);
    __syncthreads();
    gn_rowpass(xb, rr, llo, qgw, qgb);
    __syncthreads();
    #pragma unroll
    for (int mt = 0; mt < 3; mt++){ acc[mt][0] = (f32x4)0.f; acc[mt][1] = (f32x4)0.f; }
    mm_stage(xb, smem + 65536, wv, llo, lhi, acc);
    __syncthreads();
    scat_acc(xb, acc, wv, llo, lhi);
    __syncthreads();
    #pragma unroll
    for (int i = 0; i < 3; i++){
      const int row = rr[i], gr = rbase + row;
      if (gr < N_AGT){
        const uint32x4 u = *(const uint32x4*)(xb + row*256 + ((llo*16) ^ ((row&7)<<4)));
        *(uint32x4*)(QW + (size_t)gr*D + c0) = u;
      }
    }
    __syncthreads();
  }
}

// ======================= k_post_mfma (unchanged) =======================
__global__ __launch_bounds__(512, 4) void k_post_mfma(
    float* __restrict__ A0, const float* __restrict__ agts,
    const float* __restrict__ lin_w,
    const float* __restrict__ norm_gw, const float* __restrict__ norm_gb,
    const float* __restrict__ lin_gw, const float* __restrict__ lin_gb){
  extern __shared__ __align__(16) char smem[];
  const int tid  = threadIdx.x;
  const int wave = tid >> 6, lane = tid & 63;
  const int grp  = wave >> 2, wv = wave & 3;
  const int lhi  = lane >> 4, llo = lane & 15;

  stage_wsz(smem, lin_w, 128, 0, tid, 512);
  char* xb = smem + 32768 + grp*12288;
  const int c0 = llo*8;
  float ngw[8], ngb[8], lgw[8], lgb[8];
  #pragma unroll
  for (int j = 0; j < 8; j++){
    ngw[j] = norm_gw[c0+j]; ngb[j] = norm_gb[c0+j];
    lgw[j] = lin_gw[c0+j];  lgb[j] = lin_gb[c0+j];
  }
  __syncthreads();

  int rr[3];
  #pragma unroll
  for (int i = 0; i < 3; i++) rr[i] = wv*12 + i*4 + lhi;

  for (int it = blockIdx.x; it < NITER_A; it += gridDim.x){
    const int rbase = it*96 + grp*48;
    #pragma unroll
    for (int i = 0; i < 3; i++){
      const int row = rr[i];
      int gr = rbase + row; if (gr >= N_AGT) gr = N_AGT - 1;
      const float4 a0 = *(const float4*)(A0 + (size_t)gr*D + c0);
      const float4 a1 = *(const float4*)(A0 + (size_t)gr*D + c0 + 4);
      float f[8] = {a0.x,a0.y,a0.z,a0.w,a1.x,a1.y,a1.z,a1.w};
      float s = 0.f, ss = 0.f;
      #pragma unroll
      for (int j = 0; j < 8; j++){ s += f[j]; ss += f[j]*f[j]; }
      #pragma unroll
      for (int m = 1; m < 16; m <<= 1){ s += __shfl_xor(s, m); ss += __shfl_xor(ss, m); }
      const float mean = s*(1.f/128.f);
      const float var  = ss*(1.f/128.f) - mean*mean;
      const float rstd = rsqrtf(var + 1e-5f);
      ushort8 u;
      #pragma unroll
      for (int j = 0; j < 8; j++)
        u[j] = f2bf(fmaxf((f[j]-mean)*rstd*ngw[j] + ngb[j], 0.f));
      *(uint32x4*)(xb + row*256 + ((llo*16) ^ ((row&7)<<4))) =
          __builtin_bit_cast(uint32x4, u);
    }
    __syncthreads();
    f32x4 acc[3][2];
    #pragma unroll
    for (int mt = 0; mt < 3; mt++){ acc[mt][0] = (f32x4)0.f; acc[mt][1] = (f32x4)0.f; }
    mm_stage(xb, smem, wv, llo, lhi, acc);
    __syncthreads();
    scat_acc(xb, acc, wv, llo, lhi);
    __syncthreads();
    #pragma unroll
    for (int i = 0; i < 3; i++){
      const int row = rr[i];
      const char* p = xb + row*256 + ((llo*16) ^ ((row&7)<<4));
      const ushort8 u = __builtin_bit_cast(ushort8, *(const uint32x4*)p);
      float f[8]; float s = 0.f, ss = 0.f;
      #pragma unroll
      for (int j = 0; j < 8; j++){ f[j] = bf2f(u[j]); s += f[j]; ss += f[j]*f[j]; }
      #pragma unroll
      for (int m = 1; m < 16; m <<= 1){ s += __shfl_xor(s, m); ss += __shfl_xor(ss, m); }
      const float mean = s*(1.f/128.f);
      const float var  = ss*(1.f/128.f) - mean*mean;
      const float rstd = rsqrtf(var + 1e-5f);
      const int gr = rbase + row;
      if (gr < N_AGT){
        const float4 r0 = *(const float4*)(agts + (size_t)gr*D + c0);
        const float4 r1 = *(const float4*)(agts + (size_t)gr*D + c0 + 4);
        const float res[8] = {r0.x,r0.y,r0.z,r0.w,r1.x,r1.y,r1.z,r1.w};
        float o[8];
        float4 o0, o1;
        #pragma unroll
        for (int j = 0; j < 8; j++)
          o[j] = fmaxf((f[j]-mean)*rstd*lgw[j] + lgb[j] + res[j], 0.f);
        o0.x=o[0]; o0.y=o[1]; o0.z=o[2]; o0.w=o[3];
        o1.x=o[4]; o1.y=o[5]; o1.z=o[6]; o1.w=o[7];
        *(float4*)(A0 + (size_t)gr*D + c0)     = o0;
        *(float4*)(A0 + (size_t)gr*D + c0 + 4) = o1;
      }
    }
    __syncthreads();
  }
}

// ======================= k_ctx (VALU, unchanged) =======================
__device__ __forceinline__ void stage_w4(uint32_t* wp, const float* __restrict__ W,
                                         int rs, int co, int tid, int nthr){
  for (int idx = tid; idx < 32*128; idx += nthr){
    int p2 = idx & 31, o = idx >> 5;
    const float4 f = *(const float4*)(W + (size_t)o*rs + co + p2*4);
    uint32_t lo = ((uint32_t)f2bf(f.y) << 16) | (uint32_t)f2bf(f.x);
    uint32_t hi = ((uint32_t)f2bf(f.w) << 16) | (uint32_t)f2bf(f.z);
    *(uint2*)&wp[(p2*128 + o)*2] = make_uint2(lo, hi);
  }
}

__device__ __forceinline__ float dot128(const uint32_t* wp, const float* xb, int o){
  float acc = 0.f;
  #pragma unroll 8
  for (int p2 = 0; p2 < 32; p2++){
    const uint2 w = *(const uint2*)&wp[(p2*128 + o)*2];
    const float4 x = *(const float4*)&xb[p2*4];
    acc += x.x*bf_lo(w.x) + x.y*bf_hi(w.x) + x.z*bf_lo(w.y) + x.w*bf_hi(w.y);
  }
  return acc;
}

__global__ __launch_bounds__(128) void k_ctx(const float* __restrict__ ctx,
                                             const float* __restrict__ ctx_w1,
                                             uint16_t* __restrict__ CtxP){
  __shared__ __align__(16) uint32_t wc[32*128*2];
  __shared__ __align__(16) float xbuf[128];
  const int tid = threadIdx.x;
  stage_w4(wc, ctx_w1, 384, 256, tid, 128);
  __syncthreads();
  for (int row = blockIdx.x; row < N_CTX; row += gridDim.x){
    __syncthreads();
    xbuf[tid] = ctx[(size_t)row*D + tid];
    __syncthreads();
    const float acc = dot128(wc, xbuf, tid);
    CtxP[(size_t)row*D + tid] = f2bf(acc);
  }
}

extern "C" void kernel_launch(void* const* d_in, const int* in_sizes, int n_in,
                              void* d_out, int out_size, void* d_ws, size_t ws_size,
                              hipStream_t stream){
  const float* agts     = (const float*)d_in[0];
  const float* ctx      = (const float*)d_in[1];
  const float* agt_ctrs = (const float*)d_in[2];
  const float* ctx_ctrs = (const float*)d_in[3];
  const int*   hi       = (const int*)d_in[4];
  const int*   wi       = (const int*)d_in[5];
  const float* dist_w1  = (const float*)d_in[6];
  const float* dist_b1  = (const float*)d_in[7];
  const float* dist_w2  = (const float*)d_in[8];
  const float* dist_gw  = (const float*)d_in[9];
  const float* dist_gb  = (const float*)d_in[10];
  const float* q_w      = (const float*)d_in[11];
  const float* q_gw     = (const float*)d_in[12];
  const float* q_gb     = (const float*)d_in[13];
  const float* ctx_w1   = (const float*)d_in[14];
  const float* ctx_gw   = (const float*)d_in[15];
  const float* ctx_gb   = (const float*)d_in[16];
  const float* ctx_w2   = (const float*)d_in[17];
  const float* agt_w    = (const float*)d_in[18];
  const float* norm_gw  = (const float*)d_in[19];
  const float* norm_gb  = (const float*)d_in[20];
  const float* lin_w    = (const float*)d_in[21];
  const float* lin_gw   = (const float*)d_in[22];
  const float* lin_gb   = (const float*)d_in[23];

  // ws layout (bytes): QW 25.6e6 | CtxP 2.56e6 | cnt 0.4e6 | bsum 1024 |
  //                    hw 8e6 | w1dg 32768 | wc2g 32768
  uint16_t* QW   = (uint16_t*)d_ws;
  uint16_t* CtxP = QW + (size_t)N_AGT * D;
  int*      cnt  = (int*)((char*)d_ws + 28160000);
  int*      bsum = (int*)((char*)d_ws + 28560000);
  uint64_t* hw   = (uint64_t*)((char*)d_ws + 28561024);
  char*     w1dg = (char*)d_ws + 36561024;
  char*     wc2g = (char*)d_ws + 36593792;
  float*    A0   = (float*)d_out;                   // accumulator lives in d_out

  const int EDGE_LDS = 65536;
  const int APRE_LDS = 122880;
  const int POST_LDS = 57344;
  hipFuncSetAttribute((const void*)k_edge_mfma,
                      hipFuncAttributeMaxDynamicSharedMemorySize, EDGE_LDS);
  hipFuncSetAttribute((const void*)k_agent_pre_mfma,
                      hipFuncAttributeMaxDynamicSharedMemorySize, APRE_LDS);
  hipFuncSetAttribute((const void*)k_post_mfma,
                      hipFuncAttributeMaxDynamicSharedMemorySize, POST_LDS);

  // counting sort by hi -> packed (h,w) array + weight prep
  hipMemsetAsync(cnt, 0, (size_t)N_AGT*4, stream);
  k_hist<<<2048, 256, 0, stream>>>(hi, cnt);
  k_wprep<<<16, 256, 0, stream>>>(ctx_w1, ctx_w2, w1dg, wc2g);
  k_scan1<<<SCAN_B, 256, 0, stream>>>(cnt, bsum);
  k_scan2<<<1, SCAN_B, 0, stream>>>(bsum);
  k_scan3<<<SCAN_B, 256, 0, stream>>>(cnt, bsum);
  k_scatter<<<2048, 256, 0, stream>>>(hi, wi, cnt, hw);

  k_ctx<<<1024, 128, 0, stream>>>(ctx, ctx_w1, CtxP);
  k_agent_pre_mfma<<<256, 512, APRE_LDS, stream>>>(agts, q_w, ctx_w1, agt_w,
      q_gw, q_gb, QW, A0);
  k_edge_mfma<<<512, 512, EDGE_LDS, stream>>>(agt_ctrs, ctx_ctrs,
      (const uint32_t*)hw,
      dist_w1, dist_b1, dist_gw, dist_gb, ctx_gw, ctx_gb,
      dist_w2, w1dg, wc2g, QW, CtxP, A0);
  k_post_mfma<<<512, 512, POST_LDS, stream>>>(A0, agts, lin_w,
      norm_gw, norm_gb, lin_gw, lin_gb);
}

// Round 19
// 571.163 us; speedup vs baseline: 2.3286x; 2.3286x over previous
//
#include <hip/hip_runtime.h>
#include <stdint.h>

// GreatNet: agent/context edge MLP.  (R12/R17 configuration — session best, 581 us)
//   sort:           hw[pos] = packed (h,w) sorted by h (hist + 3-pass scan + scatter)
//   k_ctx:          CtxP[j]  = ctx[j] @ W1c^T                       (bf16, ws)
//   k_agent_pre_mfma: QW[i]  = relu(gn(agts[i]@q_w^T)) @ W1q^T      (bf16, ws)
//                   A0[i]    = agts[i] @ agt_w^T                    (f32, d_out)
//   k_edge_mfma:    BARRIER-FREE, SORTED: 8 waves/block (512 thr); wave owns
//                   16 sorted edges; private 4KB LDS tile; run-segmented
//                   column aggregation. Constraint map (R13-R18): >512-thr
//                   blocks or register pipelines spill (~1GB scratch); weights
//                   must be LDS-resident (L2 reads = 3x slower); so 1 block/CU
//                   @ 128 VGPR is the HIP-source optimum for this structure.
//   k_post_mfma:    a=relu(gn(A0)); t=gn(a@lin_w^T); out=relu(t+agts)

#define N_AGT 100000
#define N_CTX 10000
#define NE    1000000
#define D     128

typedef __attribute__((ext_vector_type(8))) __bf16 bf16x8;
typedef __attribute__((ext_vector_type(4))) float f32x4;
typedef __attribute__((ext_vector_type(4))) unsigned int uint32x4;
typedef __attribute__((ext_vector_type(8))) unsigned short ushort8;

__device__ __forceinline__ float bf_lo(uint32_t u){ return __uint_as_float(u << 16); }
__device__ __forceinline__ float bf_hi(uint32_t u){ return __uint_as_float(u & 0xFFFF0000u); }
__device__ __forceinline__ uint16_t f2bf(float f){
  uint32_t u = __float_as_uint(f);
  u += 0x7FFFu + ((u >> 16) & 1u);   // round-to-nearest-even
  return (uint16_t)(u >> 16);
}
__device__ __forceinline__ uint16_t f2bf_fast(float f){
  const __bf16 b = (__bf16)f;
  return __builtin_bit_cast(uint16_t, b);
}
__device__ __forceinline__ float bf2f(uint16_t v){ return __uint_as_float(((uint32_t)v) << 16); }

__device__ __forceinline__ f32x4 mfma16(bf16x8 a, bf16x8 b, f32x4 c){
  return __builtin_amdgcn_mfma_f32_16x16x32_bf16(a, b, c, 0, 0, 0);
}

// within-wave LDS ordering (write->read same buffer); NO barrier, NO vmcnt.
__device__ __forceinline__ void wave_lgkm0(){
  asm volatile("s_waitcnt lgkmcnt(0)" ::: "memory");
  __builtin_amdgcn_sched_barrier(0);   // rule #18 fence
}

// ---- shared MFMA tile machinery (swizzle: phys = row*256 + (byte ^ ((row&7)<<4))) ----

__device__ __forceinline__ void stage_wsz(char* dst, const float* __restrict__ W,
                                          int rs, int co, int tid, int nthr){
  for (int idx = tid; idx < 128*16; idx += nthr){
    const int row = idx >> 4, ch = idx & 15;
    const float4 f0 = *(const float4*)(W + (size_t)row*rs + co + ch*8);
    const float4 f1 = *(const float4*)(W + (size_t)row*rs + co + ch*8 + 4);
    ushort8 u;
    u[0]=f2bf(f0.x); u[1]=f2bf(f0.y); u[2]=f2bf(f0.z); u[3]=f2bf(f0.w);
    u[4]=f2bf(f1.x); u[5]=f2bf(f1.y); u[6]=f2bf(f1.z); u[7]=f2bf(f1.w);
    *(uint32x4*)(dst + row*256 + ((ch*16) ^ ((row&7)<<4))) = __builtin_bit_cast(uint32x4, u);
  }
}

__device__ __forceinline__ bf16x8 ldfrag(const char* base, int row, int cb){
  return __builtin_bit_cast(bf16x8,
      *(const uint32x4*)(base + row*256 + (cb ^ ((row&7)<<4))));
}

// ======================= sort-by-hi (counting sort, parallel scan) =======================
#define SCAN_B  256
#define SCAN_CH ((N_AGT + SCAN_B - 1) / SCAN_B)   // 391

__global__ __launch_bounds__(256) void k_hist(const int* __restrict__ hi,
                                              int* __restrict__ cnt){
  for (int i = blockIdx.x*256 + threadIdx.x; i < NE; i += gridDim.x*256)
    atomicAdd(&cnt[hi[i]], 1);
}

__global__ __launch_bounds__(256) void k_scan1(const int* __restrict__ cnt,
                                               int* __restrict__ bsum){
  __shared__ int red[4];
  const int b = blockIdx.x, t = threadIdx.x;
  const int lo = b*SCAN_CH, hiX = min(lo + SCAN_CH, N_AGT);
  int s = 0;
  for (int i = lo + t; i < hiX; i += 256) s += cnt[i];
  #pragma unroll
  for (int m = 1; m < 64; m <<= 1) s += __shfl_xor(s, m);
  if ((t & 63) == 0) red[t >> 6] = s;
  __syncthreads();
  if (t == 0) bsum[b] = red[0] + red[1] + red[2] + red[3];
}

__global__ __launch_bounds__(SCAN_B) void k_scan2(int* __restrict__ bsum){
  __shared__ int part[SCAN_B];
  const int t = threadIdx.x;
  const int v = bsum[t];
  part[t] = v;
  __syncthreads();
  for (int ofs = 1; ofs < SCAN_B; ofs <<= 1){
    const int add = (t >= ofs) ? part[t - ofs] : 0;
    __syncthreads();
    part[t] += add;
    __syncthreads();
  }
  bsum[t] = part[t] - v;   // exclusive
}

__global__ __launch_bounds__(256) void k_scan3(int* __restrict__ cnt,
                                               const int* __restrict__ bsum){
  __shared__ int tpart[256];
  const int b = blockIdx.x, t = threadIdx.x;
  const int lo = b*SCAN_CH, hiX = min(lo + SCAN_CH, N_AGT);
  const int per = (SCAN_CH + 255) / 256;           // 2
  const int s0 = lo + t*per, s1 = min(s0 + per, hiX);
  int s = 0;
  for (int i = s0; i < s1; i++) s += cnt[i];
  tpart[t] = s;
  __syncthreads();
  for (int ofs = 1; ofs < 256; ofs <<= 1){
    const int add = (t >= ofs) ? tpart[t - ofs] : 0;
    __syncthreads();
    tpart[t] += add;
    __syncthreads();
  }
  int run = bsum[b] + tpart[t] - s;
  for (int i = s0; i < s1; i++){
    const int c = cnt[i];
    cnt[i] = run;
    run += c;
  }
}

__global__ __launch_bounds__(256) void k_scatter(const int* __restrict__ hi,
                                                 const int* __restrict__ wi,
                                                 int* __restrict__ cur,
                                                 uint64_t* __restrict__ hw){
  for (int i = blockIdx.x*256 + threadIdx.x; i < NE; i += gridDim.x*256){
    const int h = hi[i];
    const int pos = atomicAdd(&cur[h], 1);
    hw[pos] = ((uint64_t)(uint32_t)wi[i] << 32) | (uint32_t)h;
  }
}

// ======================= k_edge_mfma (barrier-free, sorted, packed) =======================
// 512 thr = 8 waves; each wave owns 16 sorted edges/iter, private 4KB tile T.
// LDS: [0) wd2 32768 | [32768) w1d 32768 | [65536) wc2 32768
//      [98304) T: 8 waves x 4096  -> 131072 B
#define NWIT (NE/16)     // 62500 wave-iterations total (exact)

__device__ __forceinline__ void mm16(const char* T, const char* W,
                                     int llo, int lhi, f32x4 acc[8]){
  bf16x8 a[4];
  #pragma unroll
  for (int kt = 0; kt < 4; kt++) a[kt] = ldfrag(T, llo, kt*64 + lhi*16);
  #pragma unroll
  for (int nt = 0; nt < 8; nt++){
    acc[nt] = (f32x4)0.f;
    #pragma unroll
    for (int kt = 0; kt < 4; kt++){
      const bf16x8 b = ldfrag(W, nt*16 + llo, kt*64 + lhi*16);
      acc[nt] = mfma16(a[kt], b, acc[nt]);
    }
  }
}

__device__ __forceinline__ void gn_reg(f32x4 acc[8], const float gw[8],
                                       const float gb[8]){
  float s[4] = {0,0,0,0}, ss[4] = {0,0,0,0};
  #pragma unroll
  for (int nt = 0; nt < 8; nt++)
    #pragma unroll
    for (int r = 0; r < 4; r++){
      const float v = acc[nt][r];
      s[r] += v; ss[r] += v*v;
    }
  #pragma unroll
  for (int m = 1; m < 16; m <<= 1)
    #pragma unroll
    for (int r = 0; r < 4; r++){
      s[r] += __shfl_xor(s[r], m);
      ss[r] += __shfl_xor(ss[r], m);
    }
  float mean[4], rstd[4];
  #pragma unroll
  for (int r = 0; r < 4; r++){
    mean[r] = s[r]*(1.f/128.f);
    const float var = ss[r]*(1.f/128.f) - mean[r]*mean[r];
    rstd[r] = rsqrtf(var + 1e-5f);
  }
  #pragma unroll
  for (int nt = 0; nt < 8; nt++)
    #pragma unroll
    for (int r = 0; r < 4; r++)
      acc[nt][r] = fmaxf((acc[nt][r]-mean[r])*rstd[r]*gw[nt] + gb[nt], 0.f);
}

__device__ __forceinline__ void scat16(char* T, const f32x4 acc[8],
                                       int llo, int lhi){
  #pragma unroll
  for (int nt = 0; nt < 8; nt++)
    #pragma unroll
    for (int r = 0; r < 4; r++){
      const int row = lhi*4 + r;
      *(uint16_t*)(T + row*256 + ((2*(nt*16 + llo)) ^ ((row&7)<<4))) =
          f2bf_fast(acc[nt][r]);
    }
}

__global__ __launch_bounds__(512, 2) void k_edge_mfma(
    const float* __restrict__ agt_ctrs, const float* __restrict__ ctx_ctrs,
    const uint32_t* __restrict__ hw32,
    const float* __restrict__ dist_w1, const float* __restrict__ dist_b1,
    const float* __restrict__ dist_gw, const float* __restrict__ dist_gb,
    const float* __restrict__ ctx_gw, const float* __restrict__ ctx_gb,
    const float* __restrict__ dist_w2, const float* __restrict__ ctx_w1,
    const float* __restrict__ ctx_w2,
    const uint16_t* __restrict__ QW, const uint16_t* __restrict__ CtxP,
    float* __restrict__ A0){
  extern __shared__ __align__(16) char smem[];
  const int tid  = threadIdx.x;
  const int wave = tid >> 6, lane = tid & 63;
  const int lhi  = lane >> 4, llo = lane & 15;

  stage_wsz(smem,         dist_w2, 128, 0, tid, 512);
  stage_wsz(smem + 32768, ctx_w1,  384, 0, tid, 512);
  stage_wsz(smem + 65536, ctx_w2,  128, 0, tid, 512);

  char* T = smem + 98304 + wave*4096;   // private 16x256B swizzled tile

  const int c0 = llo*8;                 // d1-build cols
  float w1x[8], w1y[8], b1v[8];
  #pragma unroll
  for (int j = 0; j < 8; j++){
    w1x[j] = dist_w1[(c0+j)*2 + 0];
    w1y[j] = dist_w1[(c0+j)*2 + 1];
    b1v[j] = dist_b1[c0+j];
  }
  float dgwr[8], dgbr[8], cgwr[8], cgbr[8];   // GN cols nt*16+llo
  #pragma unroll
  for (int nt = 0; nt < 8; nt++){
    dgwr[nt] = dist_gw[nt*16 + llo]; dgbr[nt] = dist_gb[nt*16 + llo];
    cgwr[nt] = ctx_gw[nt*16 + llo];  cgbr[nt] = ctx_gb[nt*16 + llo];
  }
  __syncthreads();   // weights staged — the ONLY block barrier

  const int wid = blockIdx.x*8 + wave;
  const int nw  = gridDim.x*8;

  for (int i = wid; i < NWIT; i += nw){
    const int base = i*16;
    // ---- A: packed indices + qs-issue + d1 build into T ----
    const uint32x4 q0 = *(const uint32x4*)&hw32[2*(base + lhi*4)];      // edges +0,+1
    const uint32x4 q1 = *(const uint32x4*)&hw32[2*(base + lhi*4) + 4];  // edges +2,+3
    const int hh[4] = {(int)q0[0], (int)q0[2], (int)q1[0], (int)q1[2]};
    const int ww[4] = {(int)q0[1], (int)q0[3], (int)q1[1], (int)q1[3]};
    const uint2 p2 = *(const uint2*)&hw32[2*(base + llo)];
    const int h2 = (int)p2.x, w2 = (int)p2.y;
    uint32x4 qql[4], qcl[4];               // qs gathers: land by phase E
    #pragma unroll
    for (int k = 0; k < 4; k++){
      qql[k] = *(const uint32x4*)&QW  [(size_t)h2*D + lhi*32 + k*8];
      qcl[k] = *(const uint32x4*)&CtxP[(size_t)w2*D + lhi*32 + k*8];
    }
    #pragma unroll
    for (int j = 0; j < 4; j++){
      const float2 ac = *(const float2*)&agt_ctrs[(size_t)hh[j]*2];
      const float2 cc = *(const float2*)&ctx_ctrs[(size_t)ww[j]*2];
      const float dx = ac.x - cc.x, dy = ac.y - cc.y;
      ushort8 u;
      #pragma unroll
      for (int c = 0; c < 8; c++)
        u[c] = f2bf_fast(fmaxf(fmaf(dx, w1x[c], fmaf(dy, w1y[c], b1v[c])), 0.f));
      const int row = lhi*4 + j;
      *(uint32x4*)(T + row*256 + ((llo*16) ^ ((row&7)<<4))) =
          __builtin_bit_cast(uint32x4, u);
    }
    wave_lgkm0();                           // d1 visible to this wave
    // ---- B: mm1 z = d1 @ wd2^T ----
    f32x4 acc[8];
    mm16(T, smem, llo, lhi, acc);
    // ---- C: gn1 on regs + scatter d -> T ----
    gn_reg(acc, dgwr, dgbr);
    wave_lgkm0();                           // T reads (mm1) retired
    scat16(T, acc, llo, lhi);
    wave_lgkm0();
    // ---- D: mm2 raw = d @ w1d^T ----
    mm16(T, smem + 32768, llo, lhi, acc);
    // ---- E: qs -> T (edge-layout), read back at C positions, gn2 ----
    ushort8 qs[4];
    #pragma unroll
    for (int k = 0; k < 4; k++){
      const ushort8 a = __builtin_bit_cast(ushort8, qql[k]);
      const ushort8 b = __builtin_bit_cast(ushort8, qcl[k]);
      ushort8 v;
      #pragma unroll
      for (int j = 0; j < 8; j++) v[j] = f2bf_fast(bf2f(a[j]) + bf2f(b[j]));
      qs[k] = v;
    }
    wave_lgkm0();                           // T reads (mm2) retired
    #pragma unroll
    for (int k = 0; k < 4; k++)             // write qs: row llo, elems lhi*32+k*8
      *(uint32x4*)(T + llo*256 + (((lhi*64) + k*16) ^ ((llo&7)<<4))) =
          __builtin_bit_cast(uint32x4, qs[k]);
    wave_lgkm0();
    #pragma unroll
    for (int nt = 0; nt < 8; nt++)
      #pragma unroll
      for (int r = 0; r < 4; r++){
        const int row = lhi*4 + r;
        const uint16_t q = *(const uint16_t*)(T + row*256 +
            ((2*(nt*16 + llo)) ^ ((row&7)<<4)));
        acc[nt][r] += bf2f(q);
      }
    gn_reg(acc, cgwr, cgbr);
    wave_lgkm0();                           // qs reads retired
    scat16(T, acc, llo, lhi);               // T = c1
    wave_lgkm0();
    // ---- F: mm3 c = c1 @ wc2^T ----
    mm16(T, smem + 65536, llo, lhi, acc);
    // ---- G: scatter c -> T, run-segmented column aggregation, atomics ----
    wave_lgkm0();                           // T reads (mm3) retired
    scat16(T, acc, llo, lhi);               // T = c (bf16)
    wave_lgkm0();
    {
      const int cA = lane, cB = lane + 64;  // lane owns 2 output columns
      float runA = 0.f, runB = 0.f;
      int hprev = __shfl(h2, 0);            // hs[base] (wave-uniform)
      #pragma unroll
      for (int k = 0; k < 16; k++){
        const int hk = __shfl(h2, k);       // uniform -> scalar branch
        if (hk != hprev){
          atomicAdd(&A0[(size_t)hprev*D + cA], runA);
          atomicAdd(&A0[(size_t)hprev*D + cB], runB);
          runA = 0.f; runB = 0.f; hprev = hk;
        }
        runA += bf2f(*(const uint16_t*)(T + k*256 + ((2*cA) ^ ((k&7)<<4))));
        runB += bf2f(*(const uint16_t*)(T + k*256 + ((2*cB) ^ ((k&7)<<4))));
      }
      atomicAdd(&A0[(size_t)hprev*D + cA], runA);
      atomicAdd(&A0[(size_t)hprev*D + cB], runB);
    }
    // no barrier: next iter's T writes are in-order after this iter's T reads
  }
}

// ======================= k_agent_pre_mfma =======================
__device__ __forceinline__ void mm_stage(const char* xb, const char* wm, int wv,
                                         int llo, int lhi, f32x4 acc[3][2]){
  #pragma unroll
  for (int kt = 0; kt < 4; kt++){
    const int cb = kt*64 + lhi*16;
    const bf16x8 b0 = ldfrag(wm, wv*32 + llo,      cb);
    const bf16x8 b1 = ldfrag(wm, wv*32 + 16 + llo, cb);
    #pragma unroll
    for (int mt = 0; mt < 3; mt++){
      const bf16x8 a = ldfrag(xb, mt*16 + llo, cb);
      acc[mt][0] = mfma16(a, b0, acc[mt][0]);
      acc[mt][1] = mfma16(a, b1, acc[mt][1]);
    }
  }
}

__device__ __forceinline__ void scat_acc(char* xb, const f32x4 acc[3][2],
                                         int wv, int llo, int lhi){
  #pragma unroll
  for (int mt = 0; mt < 3; mt++)
    #pragma unroll
    for (int ntl = 0; ntl < 2; ntl++)
      #pragma unroll
      for (int r = 0; r < 4; r++){
        const int m = mt*16 + lhi*4 + r;
        const int n = wv*32 + ntl*16 + llo;
        *(uint16_t*)(xb + m*256 + ((n*2) ^ ((m&7)<<4))) = f2bf(acc[mt][ntl][r]);
      }
}

__device__ __forceinline__ void gn_rowpass(char* xb, const int rr[3], int llo,
                                           const float gw[8], const float gb[8]){
  #pragma unroll
  for (int i = 0; i < 3; i++){
    const int row = rr[i];
    char* p = xb + row*256 + ((llo*16) ^ ((row&7)<<4));
    ushort8 u = __builtin_bit_cast(ushort8, *(const uint32x4*)p);
    float f[8]; float s = 0.f, ss = 0.f;
    #pragma unroll
    for (int j = 0; j < 8; j++){ f[j] = bf2f(u[j]); s += f[j]; ss += f[j]*f[j]; }
    #pragma unroll
    for (int m = 1; m < 16; m <<= 1){ s += __shfl_xor(s, m); ss += __shfl_xor(ss, m); }
    const float mean = s*(1.f/128.f);
    const float var  = ss*(1.f/128.f) - mean*mean;
    const float rstd = rsqrtf(var + 1e-5f);
    #pragma unroll
    for (int j = 0; j < 8; j++){
      const float g = fmaxf((f[j]-mean)*rstd*gw[j] + gb[j], 0.f);
      u[j] = f2bf(g);
    }
    *(uint32x4*)p = __builtin_bit_cast(uint32x4, u);
  }
}

#define NITER_A ((N_AGT + 95) / 96)

__global__ __launch_bounds__(512, 2) void k_agent_pre_mfma(
    const float* __restrict__ agts, const float* __restrict__ q_w,
    const float* __restrict__ ctx_w1, const float* __restrict__ agt_w,
    const float* __restrict__ q_gw, const float* __restrict__ q_gb,
    uint16_t* __restrict__ QW, float* __restrict__ A0){
  extern __shared__ __align__(16) char smem[];
  const int tid  = threadIdx.x;
  const int wave = tid >> 6, lane = tid & 63;
  const int grp  = wave >> 2, wv = wave & 3;
  const int lhi  = lane >> 4, llo = lane & 15;

  stage_wsz(smem,         q_w,    128, 0,   tid, 512);
  stage_wsz(smem + 32768, agt_w,  128, 0,   tid, 512);
  stage_wsz(smem + 65536, ctx_w1, 384, 128, tid, 512);

  char* xb = smem + 98304 + grp*12288;
  const int c0 = llo*8;
  float qgw[8], qgb[8];
  #pragma unroll
  for (int j = 0; j < 8; j++){ qgw[j] = q_gw[c0+j]; qgb[j] = q_gb[c0+j]; }
  __syncthreads();

  const int tg = tid & 255;
  int rr[3];
  #pragma unroll
  for (int i = 0; i < 3; i++) rr[i] = wv*12 + i*4 + lhi;

  for (int it = blockIdx.x; it < NITER_A; it += gridDim.x){
    const int rbase = it*96 + grp*48;
    for (int idx = tg; idx < 48*32; idx += 256){
      const int row = idx >> 5, c4 = idx & 31;
      int gr = rbase + row; if (gr >= N_AGT) gr = N_AGT - 1;
      const float4 f = *(const float4*)(agts + (size_t)gr*D + c4*4);
      const uint32_t lo = ((uint32_t)f2bf(f.y) << 16) | (uint32_t)f2bf(f.x);
      const uint32_t hi2 = ((uint32_t)f2bf(f.w) << 16) | (uint32_t)f2bf(f.z);
      *(uint2*)(xb + row*256 + ((c4*8) ^ ((row&7)<<4))) = make_uint2(lo, hi2);
    }
    __syncthreads();
    f32x4 acc[3][2];
    #pragma unroll
    for (int mt = 0; mt < 3; mt++){ acc[mt][0] = (f32x4)0.f; acc[mt][1] = (f32x4)0.f; }
    mm_stage(xb, smem + 32768, wv, llo, lhi, acc);
    #pragma unroll
    for (int mt = 0; mt < 3; mt++)
      #pragma unroll
      for (int ntl = 0; ntl < 2; ntl++)
        #pragma unroll
        for (int r = 0; r < 4; r++){
          const int m = mt*16 + lhi*4 + r;
          if (rbase + m < N_AGT){
            const int n = wv*32 + ntl*16 + llo;
            A0[(size_t)(rbase + m)*D + n] = acc[mt][ntl][r];
          }
        }
    #pragma unroll
    for (int mt = 0; mt < 3; mt++){ acc[mt][0] = (f32x4)0.f; acc[mt][1] = (f32x4)0.f; }
    mm_stage(xb, smem, wv, llo, lhi, acc);
    __syncthreads();
    scat_acc(xb, acc, wv, llo, lhi);
    __syncthreads();
    gn_rowpass(xb, rr, llo, qgw, qgb);
    __syncthreads();
    #pragma unroll
    for (int mt = 0; mt < 3; mt++){ acc[mt][0] = (f32x4)0.f; acc[mt][1] = (f32x4)0.f; }
    mm_stage(xb, smem + 65536, wv, llo, lhi, acc);
    __syncthreads();
    scat_acc(xb, acc, wv, llo, lhi);
    __syncthreads();
    #pragma unroll
    for (int i = 0; i < 3; i++){
      const int row = rr[i], gr = rbase + row;
      if (gr < N_AGT){
        const uint32x4 u = *(const uint32x4*)(xb + row*256 + ((llo*16) ^ ((row&7)<<4)));
        *(uint32x4*)(QW + (size_t)gr*D + c0) = u;
      }
    }
    __syncthreads();
  }
}

// ======================= k_post_mfma =======================
__global__ __launch_bounds__(512, 4) void k_post_mfma(
    float* __restrict__ A0, const float* __restrict__ agts,
    const float* __restrict__ lin_w,
    const float* __restrict__ norm_gw, const float* __restrict__ norm_gb,
    const float* __restrict__ lin_gw, const float* __restrict__ lin_gb){
  extern __shared__ __align__(16) char smem[];
  const int tid  = threadIdx.x;
  const int wave = tid >> 6, lane = tid & 63;
  const int grp  = wave >> 2, wv = wave & 3;
  const int lhi  = lane >> 4, llo = lane & 15;

  stage_wsz(smem, lin_w, 128, 0, tid, 512);
  char* xb = smem + 32768 + grp*12288;
  const int c0 = llo*8;
  float ngw[8], ngb[8], lgw[8], lgb[8];
  #pragma unroll
  for (int j = 0; j < 8; j++){
    ngw[j] = norm_gw[c0+j]; ngb[j] = norm_gb[c0+j];
    lgw[j] = lin_gw[c0+j];  lgb[j] = lin_gb[c0+j];
  }
  __syncthreads();

  int rr[3];
  #pragma unroll
  for (int i = 0; i < 3; i++) rr[i] = wv*12 + i*4 + lhi;

  for (int it = blockIdx.x; it < NITER_A; it += gridDim.x){
    const int rbase = it*96 + grp*48;
    #pragma unroll
    for (int i = 0; i < 3; i++){
      const int row = rr[i];
      int gr = rbase + row; if (gr >= N_AGT) gr = N_AGT - 1;
      const float4 a0 = *(const float4*)(A0 + (size_t)gr*D + c0);
      const float4 a1 = *(const float4*)(A0 + (size_t)gr*D + c0 + 4);
      float f[8] = {a0.x,a0.y,a0.z,a0.w,a1.x,a1.y,a1.z,a1.w};
      float s = 0.f, ss = 0.f;
      #pragma unroll
      for (int j = 0; j < 8; j++){ s += f[j]; ss += f[j]*f[j]; }
      #pragma unroll
      for (int m = 1; m < 16; m <<= 1){ s += __shfl_xor(s, m); ss += __shfl_xor(ss, m); }
      const float mean = s*(1.f/128.f);
      const float var  = ss*(1.f/128.f) - mean*mean;
      const float rstd = rsqrtf(var + 1e-5f);
      ushort8 u;
      #pragma unroll
      for (int j = 0; j < 8; j++)
        u[j] = f2bf(fmaxf((f[j]-mean)*rstd*ngw[j] + ngb[j], 0.f));
      *(uint32x4*)(xb + row*256 + ((llo*16) ^ ((row&7)<<4))) =
          __builtin_bit_cast(uint32x4, u);
    }
    __syncthreads();
    f32x4 acc[3][2];
    #pragma unroll
    for (int mt = 0; mt < 3; mt++){ acc[mt][0] = (f32x4)0.f; acc[mt][1] = (f32x4)0.f; }
    mm_stage(xb, smem, wv, llo, lhi, acc);
    __syncthreads();
    scat_acc(xb, acc, wv, llo, lhi);
    __syncthreads();
    #pragma unroll
    for (int i = 0; i < 3; i++){
      const int row = rr[i];
      const char* p = xb + row*256 + ((llo*16) ^ ((row&7)<<4));
      const ushort8 u = __builtin_bit_cast(ushort8, *(const uint32x4*)p);
      float f[8]; float s = 0.f, ss = 0.f;
      #pragma unroll
      for (int j = 0; j < 8; j++){ f[j] = bf2f(u[j]); s += f[j]; ss += f[j]*f[j]; }
      #pragma unroll
      for (int m = 1; m < 16; m <<= 1){ s += __shfl_xor(s, m); ss += __shfl_xor(ss, m); }
      const float mean = s*(1.f/128.f);
      const float var  = ss*(1.f/128.f) - mean*mean;
      const float rstd = rsqrtf(var + 1e-5f);
      const int gr = rbase + row;
      if (gr < N_AGT){
        const float4 r0 = *(const float4*)(agts + (size_t)gr*D + c0);
        const float4 r1 = *(const float4*)(agts + (size_t)gr*D + c0 + 4);
        const float res[8] = {r0.x,r0.y,r0.z,r0.w,r1.x,r1.y,r1.z,r1.w};
        float o[8];
        float4 o0, o1;
        #pragma unroll
        for (int j = 0; j < 8; j++)
          o[j] = fmaxf((f[j]-mean)*rstd*lgw[j] + lgb[j] + res[j], 0.f);
        o0.x=o[0]; o0.y=o[1]; o0.z=o[2]; o0.w=o[3];
        o1.x=o[4]; o1.y=o[5]; o1.z=o[6]; o1.w=o[7];
        *(float4*)(A0 + (size_t)gr*D + c0)     = o0;
        *(float4*)(A0 + (size_t)gr*D + c0 + 4) = o1;
      }
    }
    __syncthreads();
  }
}

// ======================= k_ctx (VALU) =======================
__device__ __forceinline__ void stage_w4(uint32_t* wp, const float* __restrict__ W,
                                         int rs, int co, int tid, int nthr){
  for (int idx = tid; idx < 32*128; idx += nthr){
    int p2 = idx & 31, o = idx >> 5;
    const float4 f = *(const float4*)(W + (size_t)o*rs + co + p2*4);
    uint32_t lo = ((uint32_t)f2bf(f.y) << 16) | (uint32_t)f2bf(f.x);
    uint32_t hi = ((uint32_t)f2bf(f.w) << 16) | (uint32_t)f2bf(f.z);
    *(uint2*)&wp[(p2*128 + o)*2] = make_uint2(lo, hi);
  }
}

__device__ __forceinline__ float dot128(const uint32_t* wp, const float* xb, int o){
  float acc = 0.f;
  #pragma unroll 8
  for (int p2 = 0; p2 < 32; p2++){
    const uint2 w = *(const uint2*)&wp[(p2*128 + o)*2];
    const float4 x = *(const float4*)&xb[p2*4];
    acc += x.x*bf_lo(w.x) + x.y*bf_hi(w.x) + x.z*bf_lo(w.y) + x.w*bf_hi(w.y);
  }
  return acc;
}

__global__ __launch_bounds__(128) void k_ctx(const float* __restrict__ ctx,
                                             const float* __restrict__ ctx_w1,
                                             uint16_t* __restrict__ CtxP){
  __shared__ __align__(16) uint32_t wc[32*128*2];
  __shared__ __align__(16) float xbuf[128];
  const int tid = threadIdx.x;
  stage_w4(wc, ctx_w1, 384, 256, tid, 128);
  __syncthreads();
  for (int row = blockIdx.x; row < N_CTX; row += gridDim.x){
    __syncthreads();
    xbuf[tid] = ctx[(size_t)row*D + tid];
    __syncthreads();
    const float acc = dot128(wc, xbuf, tid);
    CtxP[(size_t)row*D + tid] = f2bf(acc);
  }
}

extern "C" void kernel_launch(void* const* d_in, const int* in_sizes, int n_in,
                              void* d_out, int out_size, void* d_ws, size_t ws_size,
                              hipStream_t stream){
  const float* agts     = (const float*)d_in[0];
  const float* ctx      = (const float*)d_in[1];
  const float* agt_ctrs = (const float*)d_in[2];
  const float* ctx_ctrs = (const float*)d_in[3];
  const int*   hi       = (const int*)d_in[4];
  const int*   wi       = (const int*)d_in[5];
  const float* dist_w1  = (const float*)d_in[6];
  const float* dist_b1  = (const float*)d_in[7];
  const float* dist_w2  = (const float*)d_in[8];
  const float* dist_gw  = (const float*)d_in[9];
  const float* dist_gb  = (const float*)d_in[10];
  const float* q_w      = (const float*)d_in[11];
  const float* q_gw     = (const float*)d_in[12];
  const float* q_gb     = (const float*)d_in[13];
  const float* ctx_w1   = (const float*)d_in[14];
  const float* ctx_gw   = (const float*)d_in[15];
  const float* ctx_gb   = (const float*)d_in[16];
  const float* ctx_w2   = (const float*)d_in[17];
  const float* agt_w    = (const float*)d_in[18];
  const float* norm_gw  = (const float*)d_in[19];
  const float* norm_gb  = (const float*)d_in[20];
  const float* lin_w    = (const float*)d_in[21];
  const float* lin_gw   = (const float*)d_in[22];
  const float* lin_gb   = (const float*)d_in[23];

  // ws layout (bytes): QW 25.6e6 | CtxP 2.56e6 | cnt 0.4e6 | bsum 1024 | hw 8e6
  uint16_t* QW   = (uint16_t*)d_ws;
  uint16_t* CtxP = QW + (size_t)N_AGT * D;
  int*      cnt  = (int*)((char*)d_ws + 28160000);
  int*      bsum = (int*)((char*)d_ws + 28560000);
  uint64_t* hw   = (uint64_t*)((char*)d_ws + 28561024);
  float*    A0   = (float*)d_out;                   // accumulator lives in d_out

  const int EDGE_LDS = 131072;
  const int APRE_LDS = 122880;
  const int POST_LDS = 57344;
  hipFuncSetAttribute((const void*)k_edge_mfma,
                      hipFuncAttributeMaxDynamicSharedMemorySize, EDGE_LDS);
  hipFuncSetAttribute((const void*)k_agent_pre_mfma,
                      hipFuncAttributeMaxDynamicSharedMemorySize, APRE_LDS);
  hipFuncSetAttribute((const void*)k_post_mfma,
                      hipFuncAttributeMaxDynamicSharedMemorySize, POST_LDS);

  // counting sort by hi -> packed (h,w) array
  hipMemsetAsync(cnt, 0, (size_t)N_AGT*4, stream);
  k_hist<<<2048, 256, 0, stream>>>(hi, cnt);
  k_scan1<<<SCAN_B, 256, 0, stream>>>(cnt, bsum);
  k_scan2<<<1, SCAN_B, 0, stream>>>(bsum);
  k_scan3<<<SCAN_B, 256, 0, stream>>>(cnt, bsum);
  k_scatter<<<2048, 256, 0, stream>>>(hi, wi, cnt, hw);

  k_ctx<<<1024, 128, 0, stream>>>(ctx, ctx_w1, CtxP);
  k_agent_pre_mfma<<<256, 512, APRE_LDS, stream>>>(agts, q_w, ctx_w1, agt_w,
      q_gw, q_gb, QW, A0);
  k_edge_mfma<<<256, 512, EDGE_LDS, stream>>>(agt_ctrs, ctx_ctrs,
      (const uint32_t*)hw,
      dist_w1, dist_b1, dist_gw, dist_gb, ctx_gw, ctx_gb,
      dist_w2, ctx_w1, ctx_w2, QW, CtxP, A0);
  k_post_mfma<<<512, 512, POST_LDS, stream>>>(A0, agts, lin_w,
      norm_gw, norm_gb, lin_gw, lin_gb);
}